// Round 5
// baseline (499.929 us; speedup 1.0000x reference)
//
#include <hip/hip_runtime.h>
#include <hip/hip_bf16.h>

// ManifoldHyperConnections: T=4096 rows, K=16384, 24 output cols + sumsq,
// then per-row 4x4 Sinkhorn (400 iters).
//
// R5: LDS-pipe relief. Model: w broadcast = 6 ds_read_b128 per (wave,k) =
// ~72 cyc on the per-CU DS pipe; at 2 rows/lane that's ~71 us/CU -- the
// hidden bottleneck (VALU 16%, HBM 15% both idle). Fix: 4 rows/lane
// (R=4) halves DS to ~42 us. Block owns 256 rows x 512 k; LDS tile
// [256 rows][32 k +1 pad] fp32 (36.8 KB) staged with b128 writes via
// register prefetch pipeline; compute: lane reads rows lane+64m (2-way
// bank aliasing = free), w broadcast amortized over 4 rows (100 FMA per
// 6 b128). sumsq computed in compute phase from LDS (exact fp32).

#define TROWS 4096
#define KDIM  16384
#define NOUT  24
#define RG    256                 // rows per workgroup (4 per lane)
#define KC    32                  // split-K chunks
#define KPER  (KDIM / KC)         // 512 k per workgroup
#define TILEK 32                  // k per LDS tile
#define NTILE (KPER / TILEK)      // 16 tiles
#define XSTR  (TILEK + 1)         // 33: bank = (row + k) % 32 on reads

__device__ __forceinline__ float fast_rcp(float x)   { return __builtin_amdgcn_rcpf(x); }
__device__ __forceinline__ float fast_rsqrt(float x) { return __builtin_amdgcn_rsqf(x); }

__global__ __launch_bounds__(256, 2) void gemv_part(const float* __restrict__ x,
                                                    const float* __restrict__ w,
                                                    float* __restrict__ hacc) {
    __shared__ float xs[RG * XSTR];      // [row][k], 33.8 KB
    __shared__ float wt[TILEK * NOUT];   // [k][j],    3 KB

    const int bid  = blockIdx.x;
    const int rb   = bid & 15;        // row block 0..15
    const int kc   = bid >> 4;        // split-K chunk 0..31
    const int rg0  = rb * RG;
    const int k0   = kc * KPER;

    const int t    = threadIdx.x;
    const int wv   = t >> 6;          // wave 0..3 -> k slice (8 k each)
    const int lane = t & 63;

    // staging map: thread covers rows {32s + (t>>3)}, f4 index t&7
    const int srow = t >> 3;          // 0..31 base row
    const int sf4  = t & 7;           // float4 index within 32-k tile row
    const int kk   = sf4 * 4;

    float acc[4][NOUT + 1];
#pragma unroll
    for (int m = 0; m < 4; ++m)
#pragma unroll
        for (int j = 0; j <= NOUT; ++j) acc[m][j] = 0.0f;

    const float* xg = x + (size_t)rg0 * KDIM + k0;

    // ---- prefetch tile 0 into registers ----
    float4 px[8];
    float4 pw;
    {
#pragma unroll
        for (int s = 0; s < 8; ++s)
            px[s] = *(const float4*)(xg + (size_t)(32 * s + srow) * KDIM + kk);
        const float4* wg4 = (const float4*)(w + (size_t)k0 * NOUT);
        pw = (t < 192) ? wg4[t] : make_float4(0.f, 0.f, 0.f, 0.f);
    }

#pragma unroll 1
    for (int tile = 0; tile < NTILE; ++tile) {
        __syncthreads();
        // ---- write prefetched tile into LDS (regs -> LDS, b128 stores) ----
#pragma unroll
        for (int s = 0; s < 8; ++s)
            *(float4*)(xs + (32 * s + srow) * XSTR + kk) = px[s];
        if (t < 192) ((float4*)wt)[t] = pw;
        __syncthreads();

        // ---- issue prefetch for tile+1 (in flight during compute) ----
        const int tn  = (tile + 1 < NTILE) ? tile + 1 : tile;
        const int ktn = tn * TILEK;
#pragma unroll
        for (int s = 0; s < 8; ++s)
            px[s] = *(const float4*)(xg + (size_t)(32 * s + srow) * KDIM + ktn + kk);
        {
            const float4* wg4 = (const float4*)(w + (size_t)(k0 + ktn) * NOUT);
            pw = (t < 192) ? wg4[t] : pw;
        }

        // ---- compute: wave wv -> k-local wv*8 + u; lane holds 4 rows ----
#pragma unroll
        for (int u = 0; u < 8; ++u) {
            const int kl = wv * 8 + u;
            const float* xr = xs + kl;            // + row*XSTR per row
            const float x0 = xr[(lane      ) * XSTR];
            const float x1 = xr[(lane +  64) * XSTR];
            const float x2 = xr[(lane + 128) * XSTR];
            const float x3 = xr[(lane + 192) * XSTR];
            const float4* wr = (const float4*)(wt + kl * NOUT);  // uniform -> broadcast
            float wbuf[24];
            *(float4*)(wbuf +  0) = wr[0];
            *(float4*)(wbuf +  4) = wr[1];
            *(float4*)(wbuf +  8) = wr[2];
            *(float4*)(wbuf + 12) = wr[3];
            *(float4*)(wbuf + 16) = wr[4];
            *(float4*)(wbuf + 20) = wr[5];
            acc[0][NOUT] = fmaf(x0, x0, acc[0][NOUT]);
            acc[1][NOUT] = fmaf(x1, x1, acc[1][NOUT]);
            acc[2][NOUT] = fmaf(x2, x2, acc[2][NOUT]);
            acc[3][NOUT] = fmaf(x3, x3, acc[3][NOUT]);
#pragma unroll
            for (int j = 0; j < NOUT; ++j) {
                acc[0][j] = fmaf(wbuf[j], x0, acc[0][j]);
                acc[1][j] = fmaf(wbuf[j], x1, acc[1][j]);
                acc[2][j] = fmaf(wbuf[j], x2, acc[2][j]);
                acc[3][j] = fmaf(wbuf[j], x3, acc[3][j]);
            }
        }
    }

    // combine split-K partials; hacc[j][row], lanes write consecutive addrs
#pragma unroll
    for (int m = 0; m < 4; ++m)
#pragma unroll
        for (int j = 0; j <= NOUT; ++j)
            atomicAdd(hacc + (size_t)j * TROWS + rg0 + 64 * m + lane, acc[m][j]);
}

__global__ __launch_bounds__(64) void sinkhorn_epilogue(const float* __restrict__ hacc,
                                                        const float* __restrict__ bias,
                                                        const float* __restrict__ alpha,
                                                        float* __restrict__ out) {
    const int row = blockIdx.x * 64 + threadIdx.x;

    float h[25];
#pragma unroll
    for (int j = 0; j < 25; ++j) h[j] = hacc[(size_t)j * TROWS + row];

    const float r_inv = fast_rsqrt(h[24] * (1.0f / (float)KDIM));
    const float a0 = alpha[0], a1 = alpha[1], a2 = alpha[2];

#pragma unroll
    for (int i = 0; i < 4; ++i) {
        const float zpre = fmaf(r_inv * a0, h[i], bias[i]);
        out[(size_t)row * 4 + i] = fast_rcp(1.0f + __expf(-zpre));
        const float zpo = fmaf(r_inv * a1, h[4 + i], bias[4 + i]);
        out[(size_t)16384 + (size_t)row * 4 + i] = 2.0f * fast_rcp(1.0f + __expf(-zpo));
    }

    float E[16];
#pragma unroll
    for (int t = 0; t < 16; ++t)
        E[t] = __expf(fmaf(r_inv * a2, h[8 + t], bias[8 + t]));

    float u0 = 1.0f, u1 = 1.0f, u2 = 1.0f, u3 = 1.0f;
    float v0 = 1.0f, v1 = 1.0f, v2 = 1.0f, v3 = 1.0f;

#pragma unroll 1
    for (int it = 0; it < 400; ++it) {
        float s0 = fmaf(E[0],  v0, fmaf(E[1],  v1, fmaf(E[2],  v2, E[3]  * v3)));
        float s1 = fmaf(E[4],  v0, fmaf(E[5],  v1, fmaf(E[6],  v2, E[7]  * v3)));
        float s2 = fmaf(E[8],  v0, fmaf(E[9],  v1, fmaf(E[10], v2, E[11] * v3)));
        float s3 = fmaf(E[12], v0, fmaf(E[13], v1, fmaf(E[14], v2, E[15] * v3)));
        u0 = fast_rcp(s0 + 1e-12f);
        u1 = fast_rcp(s1 + 1e-12f);
        u2 = fast_rcp(s2 + 1e-12f);
        u3 = fast_rcp(s3 + 1e-12f);
        float t0 = fmaf(E[0], u0, fmaf(E[4], u1, fmaf(E[8],  u2, E[12] * u3)));
        float t1 = fmaf(E[1], u0, fmaf(E[5], u1, fmaf(E[9],  u2, E[13] * u3)));
        float t2 = fmaf(E[2], u0, fmaf(E[6], u1, fmaf(E[10], u2, E[14] * u3)));
        float t3 = fmaf(E[3], u0, fmaf(E[7], u1, fmaf(E[11], u2, E[15] * u3)));
        v0 = fast_rcp(t0 + 1e-12f);
        v1 = fast_rcp(t1 + 1e-12f);
        v2 = fast_rcp(t2 + 1e-12f);
        v3 = fast_rcp(t3 + 1e-12f);
    }

    const size_t ob = 32768 + (size_t)row * 16;
    out[ob + 0]  = u0 * E[0]  * v0;
    out[ob + 1]  = u0 * E[1]  * v1;
    out[ob + 2]  = u0 * E[2]  * v2;
    out[ob + 3]  = u0 * E[3]  * v3;
    out[ob + 4]  = u1 * E[4]  * v0;
    out[ob + 5]  = u1 * E[5]  * v1;
    out[ob + 6]  = u1 * E[6]  * v2;
    out[ob + 7]  = u1 * E[7]  * v3;
    out[ob + 8]  = u2 * E[8]  * v0;
    out[ob + 9]  = u2 * E[9]  * v1;
    out[ob + 10] = u2 * E[10] * v2;
    out[ob + 11] = u2 * E[11] * v3;
    out[ob + 12] = u3 * E[12] * v0;
    out[ob + 13] = u3 * E[13] * v1;
    out[ob + 14] = u3 * E[14] * v2;
    out[ob + 15] = u3 * E[15] * v3;
}

extern "C" void kernel_launch(void* const* d_in, const int* in_sizes, int n_in,
                              void* d_out, int out_size, void* d_ws, size_t ws_size,
                              hipStream_t stream) {
    const float* x     = (const float*)d_in[0];
    const float* w     = (const float*)d_in[1];
    const float* bias  = (const float*)d_in[2];
    const float* alpha = (const float*)d_in[3];
    float* out  = (float*)d_out;
    float* hacc = (float*)d_ws;   // 25 * 4096 floats = 400 KB

    hipMemsetAsync(hacc, 0, (size_t)(NOUT + 1) * TROWS * sizeof(float), stream);
    gemv_part<<<dim3(16 * KC), dim3(256), 0, stream>>>(x, w, hacc);
    sinkhorn_epilogue<<<dim3(TROWS / 64), dim3(64), 0, stream>>>(hacc, bias, alpha, out);
}